// Round 4
// baseline (212.658 us; speedup 1.0000x reference)
//
#include <hip/hip_runtime.h>
#include <math.h>

// Problem constants (fixed by reference)
#define B_TOT   256
#define N_TOT   2304
#define IN_DIM  8
#define NC      10      // NUM_CLASSES
#define OD      16      // OUT_DIM
#define CD      160     // NC*OD
#define RBIAS   0.1f

// Grid: 512 blocks = 2/CU (20 waves/CU), CU-paired on same n-range (R3).
#define BTILE    64                      // b per block (= wave lanes)
#define NS       128                     // n-slices
#define NPB      (N_TOT / NS)            // 18 n per block
#define NTHREADS 640                     // 10 waves
#define XR       (NPB * IN_DIM + 4)      // 148: x row stride
#define LB       72                      // logit board row stride
#define NF4      (B_TOT * CD / 4)        // 10240 float4 per partial slab
#define WROW     (IN_DIM * CD)           // 1280 floats per W row

#define NXCD     8

// Reduce: 1280 blocks × 256 thr = 5 blk/CU balanced
#define RCOLS    8
#define RGRPS    32
#define RYPER    (NS / RGRPS)            // 4

// async global->LDS, 16B per lane; dst is wave-uniform base + lane*16 (HW rule)
#define GLDS16(gp, lp) __builtin_amdgcn_global_load_lds(                 \
    (const __attribute__((address_space(1))) void*)(gp),                  \
    (__attribute__((address_space(3))) void*)(lp), 16, 0, 0)

// ===== Routing round, R4: W via LDS broadcast instead of scalar K$ loads.
// R3 post-mortem: SGPR=96 < 128 W floats/nn -> compiler emits ~5 dependent
// s_load->waitcnt->FMA chunks per nn per wave; K$ streams 1.5MB/round so
// every chunk is a miss round-trip. Round-0 (no softmax) at VALUBusy 20%,
// same 49us as rounds 1/2 = pure scalar-chain stall. New transport:
//   waves 0..4 stage W row nn+1 (5120B, 1024B each) into LDS double-buffer
//   via global_load_lds (vector path, L2-local by XCD swizzle); all 10
//   waves read their 512B class slice as same-address broadcast
//   ds_read_b128 (conflict-free). Bit-identical arithmetic to R3.
template <int FIRST>
__global__ __launch_bounds__(NTHREADS, 5) void routing_round(
    const float* __restrict__ x,      // [B, N, 8]
    const float* __restrict__ W,      // [N, 8, 160]
    const float* __restrict__ S_acc,  // [B, 160]
    float* __restrict__ part)         // [NS, B, 160]
{
    __shared__ __align__(16) float sh_x[BTILE * XR];   // 37.9 KB
    __shared__ __align__(16) float sh_w[2][WROW];      // 10.2 KB dbuf
    __shared__ float sh_lg[2][NC * LB];                // 5.8 KB
    // total 53.9 KB -> 2 blocks/CU fits (108 < 160 KB)

    const int tid = threadIdx.x;

    const int o      = blockIdx.x;                 // 0..511
    const int xcd    = o & (NXCD - 1);
    const int r      = o >> 3;                     // 0..63 within-XCD rank
    const int cuslot = r & 31;
    const int pairid = r >> 5;                     // the two blocks on a CU
    const int ySlab  = xcd * 16 + (cuslot & 15);   // 0..127
    const int b0     = ((cuslot >> 4) * 2 + pairid) * BTILE;
    const int n0     = ySlab * NPB;

    const int b   = tid & 63;
    const int cu  = __builtin_amdgcn_readfirstlane(tid >> 6);

    // issue W row-0 stage early (waves 0..4: 1024B each, lane b -> 16B)
    if (cu < 5)
        GLDS16(W + (size_t)n0 * WROW + cu * 256 + b * 4, &sh_w[0][cu * 256]);

    // ---- stage x tile: [64 b][144 floats], coalesced float4
    {
        const int XT4 = BTILE * (NPB * IN_DIM / 4);   // 2304
        for (int k = tid; k < XT4; k += NTHREADS) {
            int bb   = k / (NPB * 2);
            int off4 = k - bb * (NPB * 2);
            float4 v = *(const float4*)(x + ((size_t)(b0 + bb) * N_TOT + n0) * IN_DIM + off4 * 4);
            *(float4*)(&sh_x[bb * XR + off4 * 4]) = v;
        }
    }

    // ---- S fragment: all 16 d for (b, c)
    float S[OD];
    if (!FIRST) {
        const float4* sp = (const float4*)(S_acc + (size_t)(b0 + b) * CD + cu * OD);
        #pragma unroll
        for (int q = 0; q < 4; q++) ((float4*)S)[q] = sp[q];
    }

    float acc[OD];
    #pragma unroll
    for (int d = 0; d < OD; d++) acc[d] = 0.f;

    asm volatile("s_waitcnt vmcnt(0)" ::: "memory");   // W row0 + x staged
    __syncthreads();

    for (int nn = 0; nn < NPB; nn++) {
        const int cur = nn & 1;

        // prefetch next W row into the other buffer (has whole nn to land)
        if (cu < 5 && nn + 1 < NPB)
            GLDS16(W + (size_t)(n0 + nn + 1) * WROW + cu * 256 + b * 4,
                   &sh_w[cur ^ 1][cu * 256]);

        float xf[IN_DIM];
        {
            const float4* xp = (const float4*)(&sh_x[b * XR + nn * IN_DIM]);
            ((float4*)xf)[0] = xp[0];
            ((float4*)xf)[1] = xp[1];
        }

        // u = x . W  — W slice via broadcast ds_read_b128 (same addr all lanes)
        const float* wb = &sh_w[cur][cu * OD];
        float u[OD];
        #pragma unroll
        for (int d = 0; d < OD; d++) u[d] = 0.f;
        #pragma unroll
        for (int i = 0; i < IN_DIM; i++) {
            const float4* wp = (const float4*)(wb + i * CD);
            const float4 wa = wp[0], wbv = wp[1], wcv = wp[2], wdv = wp[3];
            const float xi = xf[i];
            u[0]  = fmaf(xi, wa.x,  u[0]);  u[1]  = fmaf(xi, wa.y,  u[1]);
            u[2]  = fmaf(xi, wa.z,  u[2]);  u[3]  = fmaf(xi, wa.w,  u[3]);
            u[4]  = fmaf(xi, wbv.x, u[4]);  u[5]  = fmaf(xi, wbv.y, u[5]);
            u[6]  = fmaf(xi, wbv.z, u[6]);  u[7]  = fmaf(xi, wbv.w, u[7]);
            u[8]  = fmaf(xi, wcv.x, u[8]);  u[9]  = fmaf(xi, wcv.y, u[9]);
            u[10] = fmaf(xi, wcv.z, u[10]); u[11] = fmaf(xi, wcv.w, u[11]);
            u[12] = fmaf(xi, wdv.x, u[12]); u[13] = fmaf(xi, wdv.y, u[13]);
            u[14] = fmaf(xi, wdv.z, u[14]); u[15] = fmaf(xi, wdv.w, u[15]);
        }

        if (!FIRST) {
            float lg = 0.f;
            #pragma unroll
            for (int d = 0; d < OD; d++) lg = fmaf(u[d], S[d], lg);
            sh_lg[cur][cu * LB + b] = lg;
            // single barrier per nn: publishes logit board AND next W buffer
            asm volatile("s_waitcnt vmcnt(0)" ::: "memory");
            __syncthreads();

            float m = -1e30f;
            float row[NC];
            #pragma unroll
            for (int k = 0; k < NC; k++) {
                row[k] = sh_lg[cur][k * LB + b];
                m = fmaxf(m, row[k]);
            }
            float den = 0.f;
            #pragma unroll
            for (int k = 0; k < NC; k++) den += __expf(row[k] - m);
            float cw = __expf(lg - m) / den;

            #pragma unroll
            for (int d = 0; d < OD; d++) acc[d] = fmaf(cw, u[d], acc[d]);
        } else {
            #pragma unroll
            for (int d = 0; d < OD; d++) acc[d] += u[d];
            if (nn + 1 < NPB) {
                asm volatile("s_waitcnt vmcnt(0)" ::: "memory");
                __syncthreads();   // next W buffer ready; cur fully consumed
            }
        }
    }

    float* dst = part + ((size_t)ySlab * B_TOT + (b0 + b)) * CD + cu * OD;
    #pragma unroll
    for (int q = 0; q < 4; q++)
        ((float4*)dst)[q] = ((float4*)acc)[q];
}

// ===== Full-device merged reduce: 1280 blocks × 256 threads = 5 blk/CU.
// Block owns 8 float4-columns; thread (col, grp) sums 4 slabs (y = grp+32k);
// LDS combine; threads 0..7 apply scale/bias + stage B:
// store S_acc (round 0 — no memset), add (round 1), squash -> v_out (round 2).
__global__ __launch_bounds__(256) void reduce_round(
    const float* __restrict__ part,   // [NS, B, 160]
    float* __restrict__ S_acc,        // [B, 160]
    float* __restrict__ v_out,        // [B, 10, 16]
    float scale, int round)
{
    __shared__ float4 sh[RGRPS][RCOLS];   // 4 KB

    const int col = threadIdx.x & (RCOLS - 1);
    const int grp = threadIdx.x >> 3;               // 0..31
    const int g   = blockIdx.x * RCOLS + col;       // float4 column index

    const float4* p4 = (const float4*)part + (size_t)grp * NF4 + g;
    float4 s = { 0.f, 0.f, 0.f, 0.f };
    #pragma unroll
    for (int y = 0; y < RYPER; y++) {               // slabs grp, grp+32, ...
        float4 t = p4[(size_t)y * RGRPS * NF4];
        s.x += t.x; s.y += t.y; s.z += t.z; s.w += t.w;
    }
    sh[grp][col] = s;
    __syncthreads();

    if (threadIdx.x < RCOLS) {
        float4 t = { 0.f, 0.f, 0.f, 0.f };
        #pragma unroll
        for (int k = 0; k < RGRPS; k++) {
            float4 q = sh[k][col];
            t.x += q.x; t.y += q.y; t.z += q.z; t.w += q.w;
        }
        t.x = t.x * scale + RBIAS;
        t.y = t.y * scale + RBIAS;
        t.z = t.z * scale + RBIAS;
        t.w = t.w * scale + RBIAS;

        if (round == 0) {
            ((float4*)S_acc)[g] = t;          // store — no memset required
        } else if (round == 1) {
            float4 o = ((float4*)S_acc)[g];
            o.x += t.x; o.y += t.y; o.z += t.z; o.w += t.w;
            ((float4*)S_acc)[g] = o;
        } else {
            // squash: 16 d = 4 consecutive float4 columns = lanes 4k..4k+3
            float ss = t.x * t.x + t.y * t.y + t.z * t.z + t.w * t.w;
            ss += __shfl_xor(ss, 1, 64);
            ss += __shfl_xor(ss, 2, 64);
            float norm = sqrtf(ss);
            float k2 = norm / (1.0f + ss);
            float4 v = { t.x * k2, t.y * k2, t.z * k2, t.w * k2 };
            ((float4*)v_out)[g] = v;
        }
    }
}

extern "C" void kernel_launch(void* const* d_in, const int* in_sizes, int n_in,
                              void* d_out, int out_size, void* d_ws, size_t ws_size,
                              hipStream_t stream) {
    const float* x = (const float*)d_in[0];   // [256,2304,8]
    const float* W = (const float*)d_in[1];   // [2304,8,160]
    float* out = (float*)d_out;               // [256,10,16]

    // Workspace (every byte written before read each call — re-poison safe)
    float* part  = (float*)d_ws;                            // NS * 40960  (~21 MB)
    float* S_acc = part + (size_t)NS * B_TOT * CD;          // 40960 floats

    const dim3 rgrid(NS * (B_TOT / BTILE));   // 512 blocks, flat
    const int  RG = NF4 / RCOLS;              // 1280 reduce blocks — 5/CU

    // Round 0 (uniform cw; 0.1 folded into reduce scale; S_acc stored not added)
    routing_round<1><<<rgrid, NTHREADS, 0, stream>>>(x, W, S_acc, part);
    reduce_round<<<RG, 256, 0, stream>>>(part, S_acc, out, 0.1f, 0);

    // Round 1
    routing_round<0><<<rgrid, NTHREADS, 0, stream>>>(x, W, S_acc, part);
    reduce_round<<<RG, 256, 0, stream>>>(part, S_acc, out, 1.0f, 1);

    // Round 2 (+final squash fused)
    routing_round<0><<<rgrid, NTHREADS, 0, stream>>>(x, W, S_acc, part);
    reduce_round<<<RG, 256, 0, stream>>>(part, S_acc, out, 1.0f, 2);
}